// Round 5
// baseline (227.561 us; speedup 1.0000x reference)
//
#include <hip/hip_runtime.h>

// Problem constants
constexpr int Bc = 256;   // batch
constexpr int Nc = 512;   // nodes
constexpr int Dc = 256;   // dim_graph == dim_desc
constexpr int Rc = 64;    // rank
constexpr int SPLIT = 8;  // N-splits per b in the hot kernel
constexpr int ROWS = Nc / SPLIT;   // 64 rows per k1 block

// Workspace layout (floats)
constexpr size_t WS_P = 0;                       // p[B][D]         : 65536
constexpr size_t WS_L = WS_P + (size_t)Bc * Dc;  // l_part[B][S]    : 2048
constexpr size_t WS_H = WS_L + (size_t)Bc * SPLIT;            // h_part[B][S][D] : 524288
constexpr size_t WS_FLOATS = WS_H + (size_t)Bc * SPLIT * Dc;  // total 591872

// ---------------------------------------------------------------- kernel 0
// p[b][d] = sum_r (tokns_k[b]·Wq[r]) * Wk[r][d]
__global__ __launch_bounds__(256) void k0_precompute_p(
    const float* __restrict__ tokns_k, const float* __restrict__ Wq,
    const float* __restrict__ Wk, float* __restrict__ ws)
{
    const int b = blockIdx.x;
    const int t = threadIdx.x;
    const int wave = t >> 6, lane = t & 63, g = lane >> 4, l16 = lane & 15;

    __shared__ float q_s[Rc];

    #pragma unroll
    for (int step = 0; step < 4; ++step) {
        const int r = wave * 16 + step * 4 + g;
        float acc = 0.0f;
        #pragma unroll
        for (int j = 0; j < 4; ++j) {
            const float4 tk = *(const float4*)(tokns_k + b * Dc + l16 * 4 + j * 64);
            const float4 wq = *(const float4*)(Wq + r * Dc + l16 * 4 + j * 64);
            acc += tk.x * wq.x + tk.y * wq.y + tk.z * wq.z + tk.w * wq.w;
        }
        #pragma unroll
        for (int off = 1; off < 16; off <<= 1) acc += __shfl_xor(acc, off);
        if (l16 == 0) q_s[r] = acc;
    }
    __syncthreads();

    float acc = 0.0f;
    #pragma unroll 8
    for (int r = 0; r < Rc; ++r) acc += q_s[r] * Wk[r * Dc + t];
    ws[WS_P + (size_t)b * Dc + t] = acc;
}

// ---------------------------------------------------------------- kernel 1
// Pass A: 4-lane row-teams. Each lane: 16 INDEPENDENT dwordx4 loads (each
//   instruction consumes 16 whole 64B lines), dot vs LDS-broadcast p,
//   only 2 shuffles per row at the very end.
// Pass B: full-wave-per-row h accumulation, pn via LDS broadcast, zero
//   shuffles. Re-reads the block's 64KB (L2/L3-hot).
__global__ __launch_bounds__(256) void k1_stream(
    const float* __restrict__ H_pad, const int* __restrict__ mask,
    const float* __restrict__ log_scale, float* __restrict__ ws,
    float* __restrict__ out)
{
    const int s = blockIdx.x;    // split
    const int b = blockIdx.y;    // batch
    const int t = threadIdx.x;
    const int wave = t >> 6, lane = t & 63;
    const int l4   = lane & 3;          // lane within 4-lane row team
    const int roww = lane >> 2;         // row-team within wave (0..15)
    const int n0 = s * ROWS;

    __shared__ __align__(16) float p_s[Dc];
    __shared__ __align__(16) float hm[4][Dc];    // per-wave h partials
    __shared__ float pn_s[ROWS];
    __shared__ float scores_s[ROWS];
    __shared__ int   mask_s[ROWS];

    // stage p and mask
    p_s[t] = ws[WS_P + (size_t)b * Dc + t];
    if (t < ROWS) mask_s[t] = mask[b * Nc + n0 + t];
    const float inv_scale = 1.0f / fmaxf(__expf(log_scale[0]), 0.1f);
    __syncthreads();

    const float* __restrict__ Hb = H_pad + ((size_t)b * Nc + n0) * Dc;

    // ---- Pass A: scores. row = wave*16 + roww; lane covers chunks c = l4 + 4j.
    {
        const int row = wave * 16 + roww;
        const float* __restrict__ rptr = Hb + row * Dc;
        float acc = 0.0f;
        #pragma unroll
        for (int j = 0; j < 16; ++j) {
            const int c = l4 + 4 * j;                    // float4 chunk 0..63
            const float4 x  = *(const float4*)(rptr + c * 4);
            const float4 pp = *(const float4*)(p_s + c * 4);   // LDS, 4 addrs/wave: broadcast
            acc += x.x * pp.x + x.y * pp.y + x.z * pp.z + x.w * pp.w;
        }
        acc += __shfl_xor(acc, 1);
        acc += __shfl_xor(acc, 2);
        acc *= inv_scale;
        if (mask_s[row] == 0) acc = -1e30f;   // exp underflows to exact 0
        if (l4 == 0) {
            scores_s[row] = acc;
            pn_s[row] = __expf(acc);          // |scores| << 88 (validated R2-R4)
        }
    }
    __syncthreads();

    // ---- Pass B: h[d] += pn[n] * H[n][d]; wave w owns rows w*16..w*16+15.
    {
        float4 h4 = make_float4(0.f, 0.f, 0.f, 0.f);
        #pragma unroll
        for (int r = 0; r < 16; ++r) {
            const int row = wave * 16 + r;
            const float pn = pn_s[row];                        // LDS broadcast
            const float4 x = *(const float4*)(Hb + row * Dc + lane * 4);
            h4.x = fmaf(pn, x.x, h4.x);
            h4.y = fmaf(pn, x.y, h4.y);
            h4.z = fmaf(pn, x.z, h4.z);
            h4.w = fmaf(pn, x.w, h4.w);
        }
        *(float4*)(&hm[wave][lane * 4]) = h4;
    }
    __syncthreads();

    // raw scores out (k2 normalizes)
    if (t < ROWS) out[b * Nc + n0 + t] = scores_s[t];
    // L partial: butterfly over 64 pn values in wave 0
    if (t < ROWS) {
        float L = pn_s[t];
        #pragma unroll
        for (int off = 32; off >= 1; off >>= 1) L += __shfl_xor(L, off);
        if (t == 0) ws[WS_L + (size_t)b * SPLIT + s] = L;
    }
    // h partial: sum 4 wave partials per column
    ws[WS_H + ((size_t)b * SPLIT + s) * Dc + t] =
        (hm[0][t] + hm[1][t]) + (hm[2][t] + hm[3][t]);
}

// ---------------------------------------------------------------- kernel 2
// Merge partials: normalize alpha in-place, hbar, ctx = hbar @ Wv^T.
__global__ __launch_bounds__(256) void k2_merge(
    const float* __restrict__ Wv, const float* __restrict__ ws,
    float* __restrict__ out)
{
    const int b = blockIdx.x;
    const int t = threadIdx.x;
    const int wave = t >> 6, lane = t & 63, g = lane >> 4, l16 = lane & 15;

    __shared__ __align__(16) float hbar[Dc];

    float L = 0.0f;
    #pragma unroll
    for (int s = 0; s < SPLIT; ++s) L += ws[WS_L + (size_t)b * SPLIT + s];
    const float invL = 1.0f / L;

    float hacc = 0.0f;
    #pragma unroll
    for (int s = 0; s < SPLIT; ++s) hacc += ws[WS_H + ((size_t)b * SPLIT + s) * Dc + t];
    hbar[t] = hacc * invL;

    // normalize alpha in place (raw scores were written by k1)
    #pragma unroll
    for (int i = 0; i < Nc / 256; ++i) {
        const int idx = b * Nc + i * 256 + t;
        out[idx] = __expf(out[idx]) * invL;
    }
    __syncthreads();

    float4 hb4[4];
    #pragma unroll
    for (int j = 0; j < 4; ++j) hb4[j] = *(const float4*)(hbar + l16 * 4 + j * 64);
    float* __restrict__ ctx_out = out + (size_t)Bc * Nc + b * Dc;
    #pragma unroll
    for (int step = 0; step < 16; ++step) {
        const int e = step * 16 + wave * 4 + g;
        float acc = 0.0f;
        #pragma unroll
        for (int j = 0; j < 4; ++j) {
            const float4 wv = *(const float4*)(Wv + e * Dc + l16 * 4 + j * 64);
            acc += wv.x * hb4[j].x + wv.y * hb4[j].y + wv.z * hb4[j].z + wv.w * hb4[j].w;
        }
        #pragma unroll
        for (int off = 1; off < 16; off <<= 1) acc += __shfl_xor(acc, off);
        if (l16 == 0) ctx_out[e] = acc;
    }
}

// ---------------------------------------------------------------- fallback
// Round-2 single-kernel version (passed validation) for small ws_size.
constexpr int FNT = 512;
constexpr int FNW = FNT / 64;
constexpr int FNPW = Nc / FNW;

__global__ __launch_bounds__(FNT) void fba_fallback(
    const float* __restrict__ tokns_k, const float* __restrict__ H_pad,
    const int* __restrict__ mask, const float* __restrict__ Wq,
    const float* __restrict__ Wk, const float* __restrict__ Wv,
    const float* __restrict__ log_scale, float* __restrict__ out)
{
    const int b = blockIdx.x, t = threadIdx.x;
    const int wave = t >> 6, lane = t & 63;

    __shared__ __align__(16) float q_s[Rc];
    __shared__ __align__(16) float p_s[Dc];
    __shared__ __align__(16) float scores_s[Nc];
    __shared__ __align__(16) float hmerge[FNW][Dc];
    __shared__ float l_s[FNW];
    __shared__ __align__(16) float hbar[Dc];
    __shared__ int mask_s[Nc];

    const float inv_scale = 1.0f / fmaxf(__expf(log_scale[0]), 0.1f);

    const float4 tok4 = *(const float4*)(tokns_k + b * Dc + lane * 4);
    #pragma unroll
    for (int i = 0; i < Rc / FNW; ++i) {
        const int r = wave * (Rc / FNW) + i;
        const float4 w4 = *(const float4*)(Wq + r * Dc + lane * 4);
        float s = w4.x * tok4.x + w4.y * tok4.y + w4.z * tok4.z + w4.w * tok4.w;
        #pragma unroll
        for (int off = 32; off >= 1; off >>= 1) s += __shfl_xor(s, off);
        if (lane == 0) q_s[r] = s;
    }
    mask_s[t] = mask[b * Nc + t];
    mask_s[t + FNT] = mask[b * Nc + t + FNT];
    __syncthreads();

    if (t < Dc) {
        float acc = 0.0f;
        #pragma unroll 8
        for (int r = 0; r < Rc; ++r) acc += q_s[r] * Wk[r * Dc + t];
        p_s[t] = acc;
    }
    __syncthreads();

    const float4 p4 = *(const float4*)(p_s + lane * 4);
    const float* Hb = H_pad + (size_t)b * Nc * Dc;
    float l_acc = 0.0f;
    float4 h4 = make_float4(0.f, 0.f, 0.f, 0.f);

    for (int i = 0; i < FNPW; ++i) {
        const int n = wave * FNPW + i;
        const float4 x4 = *(const float4*)(Hb + n * Dc + lane * 4);
        float s = x4.x * p4.x + x4.y * p4.y + x4.z * p4.z + x4.w * p4.w;
        #pragma unroll
        for (int off = 32; off >= 1; off >>= 1) s += __shfl_xor(s, off);
        s *= inv_scale;
        if (mask_s[n] == 0) s = -1e30f;
        if (lane == 0) scores_s[n] = s;
        const float pn = __expf(s);
        l_acc += pn;
        h4.x = fmaf(pn, x4.x, h4.x); h4.y = fmaf(pn, x4.y, h4.y);
        h4.z = fmaf(pn, x4.z, h4.z); h4.w = fmaf(pn, x4.w, h4.w);
    }

    if (lane == 0) l_s[wave] = l_acc;
    *(float4*)(&hmerge[wave][lane * 4]) = h4;
    __syncthreads();

    float L = 0.0f;
    #pragma unroll
    for (int w = 0; w < FNW; ++w) L += l_s[w];
    const float invL = 1.0f / L;

    if (t < Dc) {
        float acc = 0.0f;
        #pragma unroll
        for (int w = 0; w < FNW; ++w) acc += hmerge[w][t];
        hbar[t] = acc * invL;
    }
    out[b * Nc + t] = __expf(scores_s[t]) * invL;
    out[b * Nc + t + FNT] = __expf(scores_s[t + FNT]) * invL;
    __syncthreads();

    const float4 hb4 = *(const float4*)(hbar + lane * 4);
    float* ctx_out = out + (size_t)Bc * Nc + b * Dc;
    #pragma unroll
    for (int i = 0; i < Dc / FNW; ++i) {
        const int e = wave * (Dc / FNW) + i;
        const float4 w4 = *(const float4*)(Wv + e * Dc + lane * 4);
        float s = w4.x * hb4.x + w4.y * hb4.y + w4.z * hb4.z + w4.w * hb4.w;
        #pragma unroll
        for (int off = 32; off >= 1; off >>= 1) s += __shfl_xor(s, off);
        if (lane == 0) ctx_out[e] = s;
    }
}

extern "C" void kernel_launch(void* const* d_in, const int* in_sizes, int n_in,
                              void* d_out, int out_size, void* d_ws, size_t ws_size,
                              hipStream_t stream) {
    const float* tokns_k   = (const float*)d_in[0];
    const float* H_pad     = (const float*)d_in[1];
    const int*   mask      = (const int*)d_in[2];
    const float* Wq        = (const float*)d_in[3];
    const float* Wk        = (const float*)d_in[4];
    const float* Wv        = (const float*)d_in[5];
    const float* log_scale = (const float*)d_in[6];
    float* out = (float*)d_out;

    if (ws_size >= WS_FLOATS * sizeof(float)) {
        float* ws = (float*)d_ws;
        k0_precompute_p<<<Bc, 256, 0, stream>>>(tokns_k, Wq, Wk, ws);
        dim3 grid1(SPLIT, Bc);
        k1_stream<<<grid1, 256, 0, stream>>>(H_pad, mask, log_scale, ws, out);
        k2_merge<<<Bc, 256, 0, stream>>>(Wv, ws, out);
    } else {
        fba_fallback<<<Bc, FNT, 0, stream>>>(tokns_k, H_pad, mask, Wq, Wk, Wv,
                                             log_scale, out);
    }
}

// Round 6
// 210.999 us; speedup vs baseline: 1.0785x; 1.0785x over previous
//
#include <hip/hip_runtime.h>

// Problem constants
constexpr int Bc = 256;   // batch
constexpr int Nc = 512;   // nodes
constexpr int Dc = 256;   // dim_graph == dim_desc
constexpr int Rc = 64;    // rank
constexpr int SPLIT = 8;  // N-splits per b in the hot kernel
constexpr int ROWS = Nc / SPLIT;   // 64 rows per k1 block

typedef float f4 __attribute__((ext_vector_type(4)));

// Workspace layout (floats)
constexpr size_t WS_P = 0;                       // p[B][D]         : 65536
constexpr size_t WS_L = WS_P + (size_t)Bc * Dc;  // l_part[B][S]    : 2048
constexpr size_t WS_H = WS_L + (size_t)Bc * SPLIT;            // h_part[B][S][D] : 524288
constexpr size_t WS_FLOATS = WS_H + (size_t)Bc * SPLIT * Dc;  // total 591872

// ---------------------------------------------------------------- kernel 0
// p[b][d] = sum_r (tokns_k[b]·Wq[r]) * Wk[r][d]
__global__ __launch_bounds__(256) void k0_precompute_p(
    const float* __restrict__ tokns_k, const float* __restrict__ Wq,
    const float* __restrict__ Wk, float* __restrict__ ws)
{
    const int b = blockIdx.x;
    const int t = threadIdx.x;
    const int wave = t >> 6, lane = t & 63, g = lane >> 4, l16 = lane & 15;

    __shared__ float q_s[Rc];

    #pragma unroll
    for (int step = 0; step < 4; ++step) {
        const int r = wave * 16 + step * 4 + g;
        float acc = 0.0f;
        #pragma unroll
        for (int j = 0; j < 4; ++j) {
            const float4 tk = *(const float4*)(tokns_k + b * Dc + l16 * 4 + j * 64);
            const float4 wq = *(const float4*)(Wq + r * Dc + l16 * 4 + j * 64);
            acc += tk.x * wq.x + tk.y * wq.y + tk.z * wq.z + tk.w * wq.w;
        }
        #pragma unroll
        for (int off = 1; off < 16; off <<= 1) acc += __shfl_xor(acc, off);
        if (l16 == 0) q_s[r] = acc;
    }
    __syncthreads();

    float acc = 0.0f;
    #pragma unroll 8
    for (int r = 0; r < Rc; ++r) acc += q_s[r] * Wk[r * Dc + t];
    ws[WS_P + (size_t)b * Dc + t] = acc;
}

// ---------------------------------------------------------------- kernel 1
// R3 structure (single pass over H, 16-lane teams, 4 steps) with ONE change:
// H_pad loads are NON-TEMPORAL (no-allocate streaming path).
__global__ __launch_bounds__(256) void k1_stream(
    const float* __restrict__ H_pad, const int* __restrict__ mask,
    const float* __restrict__ log_scale, float* __restrict__ ws,
    float* __restrict__ out)
{
    const int s = blockIdx.x;    // split
    const int b = blockIdx.y;    // batch
    const int t = threadIdx.x;
    const int wave = t >> 6, lane = t & 63, g = lane >> 4, l16 = lane & 15;
    const int n0 = s * ROWS;

    __shared__ __align__(16) float hm[16][Dc];   // 16 team partials, 16 KB
    __shared__ float l_s[16];
    __shared__ float scores_s[ROWS];
    __shared__ int   mask_s[ROWS];

    if (t < ROWS) mask_s[t] = mask[b * Nc + n0 + t];

    const float inv_scale = 1.0f / fmaxf(__expf(log_scale[0]), 0.1f);

    // per-lane p fragment (16 floats covering cols l16*4 + j*64)
    const float* __restrict__ pb = ws + WS_P + (size_t)b * Dc;
    float4 p4[4];
    #pragma unroll
    for (int j = 0; j < 4; ++j) p4[j] = *(const float4*)(pb + l16 * 4 + j * 64);
    __syncthreads();

    const float* __restrict__ Hb = H_pad + ((size_t)b * Nc + n0) * Dc;
    float  l_acc = 0.0f;
    float4 h4[4];
    #pragma unroll
    for (int j = 0; j < 4; ++j) h4[j] = make_float4(0.f, 0.f, 0.f, 0.f);

    #pragma unroll
    for (int step = 0; step < 4; ++step) {
        const int nr = step * 16 + wave * 4 + g;        // row within this split
        const float* __restrict__ row = Hb + nr * Dc + l16 * 4;
        f4 x[4];
        #pragma unroll
        for (int j = 0; j < 4; ++j)
            x[j] = __builtin_nontemporal_load((const f4*)(row + j * 64));

        float s0 = x[0][0] * p4[0].x + x[0][1] * p4[0].y + x[0][2] * p4[0].z + x[0][3] * p4[0].w;
        float s1 = x[1][0] * p4[1].x + x[1][1] * p4[1].y + x[1][2] * p4[1].z + x[1][3] * p4[1].w;
        float s2 = x[2][0] * p4[2].x + x[2][1] * p4[2].y + x[2][2] * p4[2].z + x[2][3] * p4[2].w;
        float s3 = x[3][0] * p4[3].x + x[3][1] * p4[3].y + x[3][2] * p4[3].z + x[3][3] * p4[3].w;
        float sc = (s0 + s1) + (s2 + s3);
        #pragma unroll
        for (int off = 1; off < 16; off <<= 1) sc += __shfl_xor(sc, off);
        sc *= inv_scale;
        if (mask_s[nr] == 0) sc = -1e30f;    // exp underflows to exact 0
        if (l16 == 0) scores_s[nr] = sc;

        const float pn = __expf(sc);         // |scores| << 88: no overflow (validated R2-R5)
        l_acc += pn;
        #pragma unroll
        for (int j = 0; j < 4; ++j) {
            h4[j].x = fmaf(pn, x[j][0], h4[j].x);
            h4[j].y = fmaf(pn, x[j][1], h4[j].y);
            h4[j].z = fmaf(pn, x[j][2], h4[j].z);
            h4[j].w = fmaf(pn, x[j][3], h4[j].w);
        }
    }

    // publish 16 team partials
    const int team = wave * 4 + g;
    #pragma unroll
    for (int j = 0; j < 4; ++j) *(float4*)(&hm[team][l16 * 4 + j * 64]) = h4[j];
    if (l16 == 0) l_s[team] = l_acc;
    __syncthreads();

    // reduce and write this block's partial
    if (t < ROWS) out[b * Nc + n0 + t] = scores_s[t];   // raw scores (k2 normalizes)
    float hsum = 0.0f;
    #pragma unroll
    for (int p = 0; p < 16; ++p) hsum += hm[p][t];
    ws[WS_H + ((size_t)b * SPLIT + s) * Dc + t] = hsum;
    if (t == 0) {
        float L = 0.0f;
        #pragma unroll
        for (int p = 0; p < 16; ++p) L += l_s[p];
        ws[WS_L + (size_t)b * SPLIT + s] = L;
    }
}

// ---------------------------------------------------------------- kernel 2
// Merge partials: normalize alpha in-place, hbar, ctx = hbar @ Wv^T.
__global__ __launch_bounds__(256) void k2_merge(
    const float* __restrict__ Wv, const float* __restrict__ ws,
    float* __restrict__ out)
{
    const int b = blockIdx.x;
    const int t = threadIdx.x;
    const int wave = t >> 6, lane = t & 63, g = lane >> 4, l16 = lane & 15;

    __shared__ __align__(16) float hbar[Dc];

    float L = 0.0f;
    #pragma unroll
    for (int s = 0; s < SPLIT; ++s) L += ws[WS_L + (size_t)b * SPLIT + s];
    const float invL = 1.0f / L;

    float hacc = 0.0f;
    #pragma unroll
    for (int s = 0; s < SPLIT; ++s) hacc += ws[WS_H + ((size_t)b * SPLIT + s) * Dc + t];
    hbar[t] = hacc * invL;

    // normalize alpha in place (raw scores were written by k1)
    #pragma unroll
    for (int i = 0; i < Nc / 256; ++i) {
        const int idx = b * Nc + i * 256 + t;
        out[idx] = __expf(out[idx]) * invL;
    }
    __syncthreads();

    float4 hb4[4];
    #pragma unroll
    for (int j = 0; j < 4; ++j) hb4[j] = *(const float4*)(hbar + l16 * 4 + j * 64);
    float* __restrict__ ctx_out = out + (size_t)Bc * Nc + b * Dc;
    #pragma unroll
    for (int step = 0; step < 16; ++step) {
        const int e = step * 16 + wave * 4 + g;
        float acc = 0.0f;
        #pragma unroll
        for (int j = 0; j < 4; ++j) {
            const float4 wv = *(const float4*)(Wv + e * Dc + l16 * 4 + j * 64);
            acc += wv.x * hb4[j].x + wv.y * hb4[j].y + wv.z * hb4[j].z + wv.w * hb4[j].w;
        }
        #pragma unroll
        for (int off = 1; off < 16; off <<= 1) acc += __shfl_xor(acc, off);
        if (l16 == 0) ctx_out[e] = acc;
    }
}

// ---------------------------------------------------------------- fallback
// Round-2 single-kernel version (passed validation) for small ws_size.
constexpr int FNT = 512;
constexpr int FNW = FNT / 64;
constexpr int FNPW = Nc / FNW;

__global__ __launch_bounds__(FNT) void fba_fallback(
    const float* __restrict__ tokns_k, const float* __restrict__ H_pad,
    const int* __restrict__ mask, const float* __restrict__ Wq,
    const float* __restrict__ Wk, const float* __restrict__ Wv,
    const float* __restrict__ log_scale, float* __restrict__ out)
{
    const int b = blockIdx.x, t = threadIdx.x;
    const int wave = t >> 6, lane = t & 63;

    __shared__ __align__(16) float q_s[Rc];
    __shared__ __align__(16) float p_s[Dc];
    __shared__ __align__(16) float scores_s[Nc];
    __shared__ __align__(16) float hmerge[FNW][Dc];
    __shared__ float l_s[FNW];
    __shared__ __align__(16) float hbar[Dc];
    __shared__ int mask_s[Nc];

    const float inv_scale = 1.0f / fmaxf(__expf(log_scale[0]), 0.1f);

    const float4 tok4 = *(const float4*)(tokns_k + b * Dc + lane * 4);
    #pragma unroll
    for (int i = 0; i < Rc / FNW; ++i) {
        const int r = wave * (Rc / FNW) + i;
        const float4 w4 = *(const float4*)(Wq + r * Dc + lane * 4);
        float s = w4.x * tok4.x + w4.y * tok4.y + w4.z * tok4.z + w4.w * tok4.w;
        #pragma unroll
        for (int off = 32; off >= 1; off >>= 1) s += __shfl_xor(s, off);
        if (lane == 0) q_s[r] = s;
    }
    mask_s[t] = mask[b * Nc + t];
    mask_s[t + FNT] = mask[b * Nc + t + FNT];
    __syncthreads();

    if (t < Dc) {
        float acc = 0.0f;
        #pragma unroll 8
        for (int r = 0; r < Rc; ++r) acc += q_s[r] * Wk[r * Dc + t];
        p_s[t] = acc;
    }
    __syncthreads();

    const float4 p4 = *(const float4*)(p_s + lane * 4);
    const float* Hb = H_pad + (size_t)b * Nc * Dc;
    float l_acc = 0.0f;
    float4 h4 = make_float4(0.f, 0.f, 0.f, 0.f);

    for (int i = 0; i < FNPW; ++i) {
        const int n = wave * FNPW + i;
        const float4 x4 = *(const float4*)(Hb + n * Dc + lane * 4);
        float s = x4.x * p4.x + x4.y * p4.y + x4.z * p4.z + x4.w * p4.w;
        #pragma unroll
        for (int off = 32; off >= 1; off >>= 1) s += __shfl_xor(s, off);
        s *= inv_scale;
        if (mask_s[n] == 0) s = -1e30f;
        if (lane == 0) scores_s[n] = s;
        const float pn = __expf(s);
        l_acc += pn;
        h4.x = fmaf(pn, x4.x, h4.x); h4.y = fmaf(pn, x4.y, h4.y);
        h4.z = fmaf(pn, x4.z, h4.z); h4.w = fmaf(pn, x4.w, h4.w);
    }

    if (lane == 0) l_s[wave] = l_acc;
    *(float4*)(&hmerge[wave][lane * 4]) = h4;
    __syncthreads();

    float L = 0.0f;
    #pragma unroll
    for (int w = 0; w < FNW; ++w) L += l_s[w];
    const float invL = 1.0f / L;

    if (t < Dc) {
        float acc = 0.0f;
        #pragma unroll
        for (int w = 0; w < FNW; ++w) acc += hmerge[w][t];
        hbar[t] = acc * invL;
    }
    out[b * Nc + t] = __expf(scores_s[t]) * invL;
    out[b * Nc + t + FNT] = __expf(scores_s[t + FNT]) * invL;
    __syncthreads();

    const float4 hb4 = *(const float4*)(hbar + lane * 4);
    float* ctx_out = out + (size_t)Bc * Nc + b * Dc;
    #pragma unroll
    for (int i = 0; i < Dc / FNW; ++i) {
        const int e = wave * (Dc / FNW) + i;
        const float4 w4 = *(const float4*)(Wv + e * Dc + lane * 4);
        float s = w4.x * hb4.x + w4.y * hb4.y + w4.z * hb4.z + w4.w * hb4.w;
        #pragma unroll
        for (int off = 32; off >= 1; off >>= 1) s += __shfl_xor(s, off);
        if (lane == 0) ctx_out[e] = s;
    }
}

extern "C" void kernel_launch(void* const* d_in, const int* in_sizes, int n_in,
                              void* d_out, int out_size, void* d_ws, size_t ws_size,
                              hipStream_t stream) {
    const float* tokns_k   = (const float*)d_in[0];
    const float* H_pad     = (const float*)d_in[1];
    const int*   mask      = (const int*)d_in[2];
    const float* Wq        = (const float*)d_in[3];
    const float* Wk        = (const float*)d_in[4];
    const float* Wv        = (const float*)d_in[5];
    const float* log_scale = (const float*)d_in[6];
    float* out = (float*)d_out;

    if (ws_size >= WS_FLOATS * sizeof(float)) {
        float* ws = (float*)d_ws;
        k0_precompute_p<<<Bc, 256, 0, stream>>>(tokns_k, Wq, Wk, ws);
        dim3 grid1(SPLIT, Bc);
        k1_stream<<<grid1, 256, 0, stream>>>(H_pad, mask, log_scale, ws, out);
        k2_merge<<<Bc, 256, 0, stream>>>(Wv, ws, out);
    } else {
        fba_fallback<<<Bc, FNT, 0, stream>>>(tokns_k, H_pad, mask, Wq, Wk, Wv,
                                             log_scale, out);
    }
}

// Round 7
// 202.768 us; speedup vs baseline: 1.1223x; 1.0406x over previous
//
#include <hip/hip_runtime.h>

// Problem constants
constexpr int Bc = 256;   // batch
constexpr int Nc = 512;   // nodes
constexpr int Dc = 256;   // dim_graph == dim_desc
constexpr int Rc = 64;    // rank
constexpr int SPLIT = 8;  // N-splits per b in the hot kernel
constexpr int ROWS = Nc / SPLIT;   // 64 rows per k1 block

typedef float f4 __attribute__((ext_vector_type(4)));

// Workspace layout (floats)
constexpr size_t WS_P = 0;                       // p[B][D]         : 65536
constexpr size_t WS_L = WS_P + (size_t)Bc * Dc;  // l_part[B][S]    : 2048
constexpr size_t WS_H = WS_L + (size_t)Bc * SPLIT;            // h_part[B][S][D] : 524288
constexpr size_t WS_FLOATS = WS_H + (size_t)Bc * SPLIT * Dc;  // total 591872

// ---------------------------------------------------------------- kernel 0
// p[b][d] = sum_r (tokns_k[b]·Wq[r]) * Wk[r][d]
__global__ __launch_bounds__(256) void k0_precompute_p(
    const float* __restrict__ tokns_k, const float* __restrict__ Wq,
    const float* __restrict__ Wk, float* __restrict__ ws)
{
    const int b = blockIdx.x;
    const int t = threadIdx.x;
    const int wave = t >> 6, lane = t & 63, g = lane >> 4, l16 = lane & 15;

    __shared__ float q_s[Rc];

    #pragma unroll
    for (int step = 0; step < 4; ++step) {
        const int r = wave * 16 + step * 4 + g;
        float acc = 0.0f;
        #pragma unroll
        for (int j = 0; j < 4; ++j) {
            const float4 tk = *(const float4*)(tokns_k + b * Dc + l16 * 4 + j * 64);
            const float4 wq = *(const float4*)(Wq + r * Dc + l16 * 4 + j * 64);
            acc += tk.x * wq.x + tk.y * wq.y + tk.z * wq.z + tk.w * wq.w;
        }
        #pragma unroll
        for (int off = 1; off < 16; off <<= 1) acc += __shfl_xor(acc, off);
        if (l16 == 0) q_s[r] = acc;
    }
    __syncthreads();

    float acc = 0.0f;
    #pragma unroll 8
    for (int r = 0; r < Rc; ++r) acc += q_s[r] * Wk[r * Dc + t];
    ws[WS_P + (size_t)b * Dc + t] = acc;
}

// ---------------------------------------------------------------- kernel 1
// R6 structure (single nt-load pass over H, 16-lane teams) with ONE change:
// masked-out rows (pn == 0 exactly) are SKIPPED entirely — no H load at all.
// Branch is at 16-lane-team granularity (whole team shares mask_s[n]), so
// exec-masking suppresses the fetch for inactive teams. Bit-identical output.
__global__ __launch_bounds__(256) void k1_stream(
    const float* __restrict__ H_pad, const int* __restrict__ mask,
    const float* __restrict__ log_scale, float* __restrict__ ws,
    float* __restrict__ out)
{
    const int s = blockIdx.x;    // split
    const int b = blockIdx.y;    // batch
    const int t = threadIdx.x;
    const int wave = t >> 6, lane = t & 63, g = lane >> 4, l16 = lane & 15;
    const int n0 = s * ROWS;

    __shared__ __align__(16) float hm[16][Dc];   // 16 team partials, 16 KB
    __shared__ float l_s[16];
    __shared__ float scores_s[ROWS];
    __shared__ int   mask_s[ROWS];

    if (t < ROWS) mask_s[t] = mask[b * Nc + n0 + t];

    const float inv_scale = 1.0f / fmaxf(__expf(log_scale[0]), 0.1f);

    // per-lane p fragment (16 floats covering cols l16*4 + j*64)
    const float* __restrict__ pb = ws + WS_P + (size_t)b * Dc;
    float4 p4[4];
    #pragma unroll
    for (int j = 0; j < 4; ++j) p4[j] = *(const float4*)(pb + l16 * 4 + j * 64);
    __syncthreads();

    const float* __restrict__ Hb = H_pad + ((size_t)b * Nc + n0) * Dc;
    float  l_acc = 0.0f;
    float4 h4[4];
    #pragma unroll
    for (int j = 0; j < 4; ++j) h4[j] = make_float4(0.f, 0.f, 0.f, 0.f);

    #pragma unroll
    for (int step = 0; step < 4; ++step) {
        const int nr = step * 16 + wave * 4 + g;        // row within this split
        if (mask_s[nr] != 0) {
            const float* __restrict__ row = Hb + nr * Dc + l16 * 4;
            f4 x[4];
            #pragma unroll
            for (int j = 0; j < 4; ++j)
                x[j] = __builtin_nontemporal_load((const f4*)(row + j * 64));

            float s0 = x[0][0] * p4[0].x + x[0][1] * p4[0].y + x[0][2] * p4[0].z + x[0][3] * p4[0].w;
            float s1 = x[1][0] * p4[1].x + x[1][1] * p4[1].y + x[1][2] * p4[1].z + x[1][3] * p4[1].w;
            float s2 = x[2][0] * p4[2].x + x[2][1] * p4[2].y + x[2][2] * p4[2].z + x[2][3] * p4[2].w;
            float s3 = x[3][0] * p4[3].x + x[3][1] * p4[3].y + x[3][2] * p4[3].z + x[3][3] * p4[3].w;
            float sc = (s0 + s1) + (s2 + s3);
            #pragma unroll
            for (int off = 1; off < 16; off <<= 1) sc += __shfl_xor(sc, off);
            sc *= inv_scale;
            if (l16 == 0) scores_s[nr] = sc;

            const float pn = __expf(sc);     // |scores| << 88: no overflow (validated R2-R6)
            l_acc += pn;
            #pragma unroll
            for (int j = 0; j < 4; ++j) {
                h4[j].x = fmaf(pn, x[j][0], h4[j].x);
                h4[j].y = fmaf(pn, x[j][1], h4[j].y);
                h4[j].z = fmaf(pn, x[j][2], h4[j].z);
                h4[j].w = fmaf(pn, x[j][3], h4[j].w);
            }
        } else {
            // masked out: alpha is exactly 0, h/l contributions exactly 0 — skip load
            if (l16 == 0) scores_s[nr] = -1e30f;
        }
    }

    // publish 16 team partials
    const int team = wave * 4 + g;
    #pragma unroll
    for (int j = 0; j < 4; ++j) *(float4*)(&hm[team][l16 * 4 + j * 64]) = h4[j];
    if (l16 == 0) l_s[team] = l_acc;
    __syncthreads();

    // reduce and write this block's partial
    if (t < ROWS) out[b * Nc + n0 + t] = scores_s[t];   // raw scores (k2 normalizes)
    float hsum = 0.0f;
    #pragma unroll
    for (int p = 0; p < 16; ++p) hsum += hm[p][t];
    ws[WS_H + ((size_t)b * SPLIT + s) * Dc + t] = hsum;
    if (t == 0) {
        float L = 0.0f;
        #pragma unroll
        for (int p = 0; p < 16; ++p) L += l_s[p];
        ws[WS_L + (size_t)b * SPLIT + s] = L;
    }
}

// ---------------------------------------------------------------- kernel 2
// Merge partials: normalize alpha in-place, hbar, ctx = hbar @ Wv^T.
__global__ __launch_bounds__(256) void k2_merge(
    const float* __restrict__ Wv, const float* __restrict__ ws,
    float* __restrict__ out)
{
    const int b = blockIdx.x;
    const int t = threadIdx.x;
    const int wave = t >> 6, lane = t & 63, g = lane >> 4, l16 = lane & 15;

    __shared__ __align__(16) float hbar[Dc];

    float L = 0.0f;
    #pragma unroll
    for (int s = 0; s < SPLIT; ++s) L += ws[WS_L + (size_t)b * SPLIT + s];
    const float invL = 1.0f / L;

    float hacc = 0.0f;
    #pragma unroll
    for (int s = 0; s < SPLIT; ++s) hacc += ws[WS_H + ((size_t)b * SPLIT + s) * Dc + t];
    hbar[t] = hacc * invL;

    // normalize alpha in place (raw scores were written by k1)
    #pragma unroll
    for (int i = 0; i < Nc / 256; ++i) {
        const int idx = b * Nc + i * 256 + t;
        out[idx] = __expf(out[idx]) * invL;
    }
    __syncthreads();

    float4 hb4[4];
    #pragma unroll
    for (int j = 0; j < 4; ++j) hb4[j] = *(const float4*)(hbar + l16 * 4 + j * 64);
    float* __restrict__ ctx_out = out + (size_t)Bc * Nc + b * Dc;
    #pragma unroll
    for (int step = 0; step < 16; ++step) {
        const int e = step * 16 + wave * 4 + g;
        float acc = 0.0f;
        #pragma unroll
        for (int j = 0; j < 4; ++j) {
            const float4 wv = *(const float4*)(Wv + e * Dc + l16 * 4 + j * 64);
            acc += wv.x * hb4[j].x + wv.y * hb4[j].y + wv.z * hb4[j].z + wv.w * hb4[j].w;
        }
        #pragma unroll
        for (int off = 1; off < 16; off <<= 1) acc += __shfl_xor(acc, off);
        if (l16 == 0) ctx_out[e] = acc;
    }
}

// ---------------------------------------------------------------- fallback
// Round-2 single-kernel version (passed validation) for small ws_size.
constexpr int FNT = 512;
constexpr int FNW = FNT / 64;
constexpr int FNPW = Nc / FNW;

__global__ __launch_bounds__(FNT) void fba_fallback(
    const float* __restrict__ tokns_k, const float* __restrict__ H_pad,
    const int* __restrict__ mask, const float* __restrict__ Wq,
    const float* __restrict__ Wk, const float* __restrict__ Wv,
    const float* __restrict__ log_scale, float* __restrict__ out)
{
    const int b = blockIdx.x, t = threadIdx.x;
    const int wave = t >> 6, lane = t & 63;

    __shared__ __align__(16) float q_s[Rc];
    __shared__ __align__(16) float p_s[Dc];
    __shared__ __align__(16) float scores_s[Nc];
    __shared__ __align__(16) float hmerge[FNW][Dc];
    __shared__ float l_s[FNW];
    __shared__ __align__(16) float hbar[Dc];
    __shared__ int mask_s[Nc];

    const float inv_scale = 1.0f / fmaxf(__expf(log_scale[0]), 0.1f);

    const float4 tok4 = *(const float4*)(tokns_k + b * Dc + lane * 4);
    #pragma unroll
    for (int i = 0; i < Rc / FNW; ++i) {
        const int r = wave * (Rc / FNW) + i;
        const float4 w4 = *(const float4*)(Wq + r * Dc + lane * 4);
        float s = w4.x * tok4.x + w4.y * tok4.y + w4.z * tok4.z + w4.w * tok4.w;
        #pragma unroll
        for (int off = 32; off >= 1; off >>= 1) s += __shfl_xor(s, off);
        if (lane == 0) q_s[r] = s;
    }
    mask_s[t] = mask[b * Nc + t];
    mask_s[t + FNT] = mask[b * Nc + t + FNT];
    __syncthreads();

    if (t < Dc) {
        float acc = 0.0f;
        #pragma unroll 8
        for (int r = 0; r < Rc; ++r) acc += q_s[r] * Wk[r * Dc + t];
        p_s[t] = acc;
    }
    __syncthreads();

    const float4 p4 = *(const float4*)(p_s + lane * 4);
    const float* Hb = H_pad + (size_t)b * Nc * Dc;
    float l_acc = 0.0f;
    float4 h4 = make_float4(0.f, 0.f, 0.f, 0.f);

    for (int i = 0; i < FNPW; ++i) {
        const int n = wave * FNPW + i;
        const float4 x4 = *(const float4*)(Hb + n * Dc + lane * 4);
        float s = x4.x * p4.x + x4.y * p4.y + x4.z * p4.z + x4.w * p4.w;
        #pragma unroll
        for (int off = 32; off >= 1; off >>= 1) s += __shfl_xor(s, off);
        s *= inv_scale;
        if (mask_s[n] == 0) s = -1e30f;
        if (lane == 0) scores_s[n] = s;
        const float pn = __expf(s);
        l_acc += pn;
        h4.x = fmaf(pn, x4.x, h4.x); h4.y = fmaf(pn, x4.y, h4.y);
        h4.z = fmaf(pn, x4.z, h4.z); h4.w = fmaf(pn, x4.w, h4.w);
    }

    if (lane == 0) l_s[wave] = l_acc;
    *(float4*)(&hmerge[wave][lane * 4]) = h4;
    __syncthreads();

    float L = 0.0f;
    #pragma unroll
    for (int w = 0; w < FNW; ++w) L += l_s[w];
    const float invL = 1.0f / L;

    if (t < Dc) {
        float acc = 0.0f;
        #pragma unroll
        for (int w = 0; w < FNW; ++w) acc += hmerge[w][t];
        hbar[t] = acc * invL;
    }
    out[b * Nc + t] = __expf(scores_s[t]) * invL;
    out[b * Nc + t + FNT] = __expf(scores_s[t + FNT]) * invL;
    __syncthreads();

    const float4 hb4 = *(const float4*)(hbar + lane * 4);
    float* ctx_out = out + (size_t)Bc * Nc + b * Dc;
    #pragma unroll
    for (int i = 0; i < Dc / FNW; ++i) {
        const int e = wave * (Dc / FNW) + i;
        const float4 w4 = *(const float4*)(Wv + e * Dc + lane * 4);
        float s = w4.x * hb4.x + w4.y * hb4.y + w4.z * hb4.z + w4.w * hb4.w;
        #pragma unroll
        for (int off = 32; off >= 1; off >>= 1) s += __shfl_xor(s, off);
        if (lane == 0) ctx_out[e] = s;
    }
}

extern "C" void kernel_launch(void* const* d_in, const int* in_sizes, int n_in,
                              void* d_out, int out_size, void* d_ws, size_t ws_size,
                              hipStream_t stream) {
    const float* tokns_k   = (const float*)d_in[0];
    const float* H_pad     = (const float*)d_in[1];
    const int*   mask      = (const int*)d_in[2];
    const float* Wq        = (const float*)d_in[3];
    const float* Wk        = (const float*)d_in[4];
    const float* Wv        = (const float*)d_in[5];
    const float* log_scale = (const float*)d_in[6];
    float* out = (float*)d_out;

    if (ws_size >= WS_FLOATS * sizeof(float)) {
        float* ws = (float*)d_ws;
        k0_precompute_p<<<Bc, 256, 0, stream>>>(tokns_k, Wq, Wk, ws);
        dim3 grid1(SPLIT, Bc);
        k1_stream<<<grid1, 256, 0, stream>>>(H_pad, mask, log_scale, ws, out);
        k2_merge<<<Bc, 256, 0, stream>>>(Wv, ws, out);
    } else {
        fba_fallback<<<Bc, FNT, 0, stream>>>(tokns_k, H_pad, mask, Wq, Wk, Wv,
                                             log_scale, out);
    }
}